// Round 6
// baseline (196.026 us; speedup 1.0000x reference)
//
#include <hip/hip_runtime.h>
#include <math.h>

#define Bn 32
#define Cn 768
#define CRn 192
#define HWn 1024   // H*W = 32*32, contiguous innermost per (b,c)
#define ROWS (Bn * Cn)

typedef float nfloat4 __attribute__((ext_vector_type(4)));  // native vec for nt store

// ---------------- Kernel 1: squeeze (mean over HW per (b,c)) ----------------
// 4 rows per block, one row per wave: lane does 4 coalesced float4 loads from
// its wave's row (4 outstanding loads -> MLP), butterfly-reduce, lane 0 writes.
// 6144 blocks (vs 24576): 4x less dispatch ramp.
__global__ __launch_bounds__(256) void se_mean(const float* __restrict__ x,
                                               float* __restrict__ s) {
    const int lane = threadIdx.x & 63;
    const int r    = blockIdx.x * 4 + (threadIdx.x >> 6);   // one row per wave
    const float4* xp = (const float4*)(x + (size_t)r * HWn);
    float4 v0 = xp[lane];
    float4 v1 = xp[lane + 64];
    float4 v2 = xp[lane + 128];
    float4 v3 = xp[lane + 192];
    float sum = (v0.x + v0.y + v0.z + v0.w) + (v1.x + v1.y + v1.z + v1.w)
              + (v2.x + v2.y + v2.z + v2.w) + (v3.x + v3.y + v3.z + v3.w);
    #pragma unroll
    for (int off = 32; off > 0; off >>= 1) sum += __shfl_xor(sum, off);
    if (lane == 0) s[r] = sum * (1.0f / (float)HWn);
}

// ---------------- Kernel 2: h = swish(s @ w1^T + b1) ------------------------
// One WAVE per (b,j) dot of length 768: 3 coalesced float4 loads per lane,
// then wave-reduce. 1536 blocks; ~2-3 us.
__global__ __launch_bounds__(256) void se_h(const float* __restrict__ s,
                                            const float* __restrict__ w1,
                                            const float* __restrict__ b1,
                                            float* __restrict__ h) {
    const int wid  = threadIdx.x >> 6;
    const int lane = threadIdx.x & 63;
    const int b = blockIdx.x / (CRn / 4);           // 4 dots per block (one per wave)
    const int j = (blockIdx.x % (CRn / 4)) * 4 + wid;

    const float4* wr = (const float4*)(w1 + (size_t)j * Cn);   // 192 float4s
    const float4* sp = (const float4*)(s + (size_t)b * Cn);
    float acc = 0.0f;
    #pragma unroll
    for (int t = 0; t < 3; ++t) {
        float4 wv = wr[lane + 64 * t];
        float4 sv = sp[lane + 64 * t];
        acc += wv.x * sv.x + wv.y * sv.y + wv.z * sv.z + wv.w * sv.w;
    }
    #pragma unroll
    for (int off = 32; off > 0; off >>= 1) acc += __shfl_down(acc, off);
    if (lane == 0) {
        float v = acc + b1[j];
        h[b * CRn + j] = v / (1.0f + expf(-v));     // swish
    }
}

// ---------------- Kernel 3: fused gate + scale ------------------------------
// 4 rows per block, one per wave (4 consecutive c, same b since 4|Cn).
// Wave issues its 4 x-float4 loads FIRST, computes its gate
// g = sigmoid(h[b,:].w2[c,:] + b2[c]) under them (h/w2 rows L1/L2-hot),
// then scales and nt-streams out. No LDS, no barriers.
__global__ __launch_bounds__(256) void se_scale_g(const float* __restrict__ x,
                                                  const float* __restrict__ h,
                                                  const float* __restrict__ w2,
                                                  const float* __restrict__ b2,
                                                  float* __restrict__ out) {
    const int lane = threadIdx.x & 63;
    const int bc   = blockIdx.x * 4 + (threadIdx.x >> 6);   // one row per wave
    const int b = bc / Cn;
    const int c = bc % Cn;

    const float4* xp = (const float4*)(x + (size_t)bc * HWn);
    float4 v0 = xp[lane];              // streaming loads in flight first
    float4 v1 = xp[lane + 64];
    float4 v2 = xp[lane + 128];
    float4 v3 = xp[lane + 192];

    const float* hp = h  + (size_t)b * CRn;
    const float* wp = w2 + (size_t)c * CRn;
    float acc = hp[lane]       * wp[lane]
              + hp[lane + 64]  * wp[lane + 64]
              + hp[lane + 128] * wp[lane + 128];
    #pragma unroll
    for (int off = 32; off > 0; off >>= 1) acc += __shfl_xor(acc, off);
    const float g = 1.0f / (1.0f + expf(-(acc + b2[c])));

    nfloat4* op = (nfloat4*)(out + (size_t)bc * HWn);
    nfloat4 n0 = { v0.x * g, v0.y * g, v0.z * g, v0.w * g };
    nfloat4 n1 = { v1.x * g, v1.y * g, v1.z * g, v1.w * g };
    nfloat4 n2 = { v2.x * g, v2.y * g, v2.z * g, v2.w * g };
    nfloat4 n3 = { v3.x * g, v3.y * g, v3.z * g, v3.w * g };
    __builtin_nontemporal_store(n0, &op[lane]);
    __builtin_nontemporal_store(n1, &op[lane + 64]);
    __builtin_nontemporal_store(n2, &op[lane + 128]);
    __builtin_nontemporal_store(n3, &op[lane + 192]);
}

extern "C" void kernel_launch(void* const* d_in, const int* in_sizes, int n_in,
                              void* d_out, int out_size, void* d_ws, size_t ws_size,
                              hipStream_t stream) {
    const float* x  = (const float*)d_in[0];
    const float* w1 = (const float*)d_in[1];
    const float* b1 = (const float*)d_in[2];
    const float* w2 = (const float*)d_in[3];
    const float* b2 = (const float*)d_in[4];
    float* out = (float*)d_out;

    float* s = (float*)d_ws;            // [B*C]  means
    float* h = s + (size_t)Bn * Cn;     // [B*Cr] hidden activations

    se_mean   <<<ROWS / 4,       256, 0, stream>>>(x, s);
    se_h      <<<Bn * (CRn / 4), 256, 0, stream>>>(s, w1, b1, h);
    se_scale_g<<<ROWS / 4,       256, 0, stream>>>(x, h, w2, b2, out);
}